// Round 5
// baseline (289.365 us; speedup 1.0000x reference)
//
#include <hip/hip_runtime.h>

#define NN 50000
#define NE 800000
#define C 128
#define CAP 64                           // fixed edge capacity per node (P(deg>=64) ~ 4e-18)
#define EP8 ((NE / 8 + 255) / 256)       // 391 edge-place blocks (8 edges/thread: 8-deep MLP per lane)
#define SPLITB 1563                      // x-split blocks
#define WB 96                            // W-split blocks: 6*16384 floats / 4 / 256
#define CB  ((NN + 255) / 256)           // 196 compact blocks (appended to fused-L0 grid)
#define ASTRIDE 136                      // bf16 elems per LDS A row

typedef __attribute__((ext_vector_type(8))) short bf16x8;
typedef __attribute__((ext_vector_type(4))) float f32x4;
typedef unsigned short ushort;

__device__ inline ushort bf16_rn(float f) {
    unsigned u = __builtin_bit_cast(unsigned, f);
    u += 0x7FFF + ((u >> 16) & 1);
    return (ushort)(u >> 16);
}
__device__ inline void split_bf16(float f, ushort& hi, ushort& lo) {
    hi = bf16_rn(f);
    float hif = __builtin_bit_cast(float, (unsigned)hi << 16);
    lo = bf16_rn(f - hif);               // residual, ~2^-17 rel total
}
__device__ inline float bf_lo(unsigned u) { return __builtin_bit_cast(float, u << 16); }
__device__ inline float bf_hi(unsigned u) { return __builtin_bit_cast(float, u & 0xFFFF0000u); }

// ---- fused prep: edge place (count+scatter+mark, 8 edges/thread) + split x (hi only) + split W ----
// Returning atomicAdd gives the bucket slot directly -> no pos array, no fill kernel.
// ILP trend measured: 2/thr=71us, 4/thr=63.5us -> 8/thr (8 independent atomic->scatter chains).

__global__ __launch_bounds__(256)
void prep_kernel(const int* __restrict__ src, const int* __restrict__ dst,
                 const float* __restrict__ x,
                 const float* __restrict__ W0, const float* __restrict__ W1,
                 const float* __restrict__ W2, const float* __restrict__ W3,
                 const float* __restrict__ W4, const float* __restrict__ W5,
                 int* __restrict__ deg, int* __restrict__ col,
                 ushort* __restrict__ Ah,
                 ushort* __restrict__ Wh, ushort* __restrict__ Wl,
                 int* __restrict__ needed, int rows_out) {
    int t = threadIdx.x;
    if (blockIdx.x < EP8) {
        int e0 = (blockIdx.x * 256 + t) * 8;
        if (e0 < NE) {
            int4 da = *(const int4*)(dst + e0);
            int4 db = *(const int4*)(dst + e0 + 4);
            int4 sa = *(const int4*)(src + e0);
            int4 sb = *(const int4*)(src + e0 + 4);
            int p0 = atomicAdd(&deg[da.x], 1);
            int p1 = atomicAdd(&deg[da.y], 1);
            int p2 = atomicAdd(&deg[da.z], 1);
            int p3 = atomicAdd(&deg[da.w], 1);
            int p4 = atomicAdd(&deg[db.x], 1);
            int p5 = atomicAdd(&deg[db.y], 1);
            int p6 = atomicAdd(&deg[db.z], 1);
            int p7 = atomicAdd(&deg[db.w], 1);
            if (p0 < CAP) col[da.x * CAP + p0] = sa.x;
            if (p1 < CAP) col[da.y * CAP + p1] = sa.y;
            if (p2 < CAP) col[da.z * CAP + p2] = sa.z;
            if (p3 < CAP) col[da.w * CAP + p3] = sa.w;
            if (p4 < CAP) col[db.x * CAP + p4] = sb.x;
            if (p5 < CAP) col[db.y * CAP + p5] = sb.y;
            if (p6 < CAP) col[db.z * CAP + p6] = sb.z;
            if (p7 < CAP) col[db.w * CAP + p7] = sb.w;
            if (da.x < rows_out) needed[sa.x] = 1;
            if (da.y < rows_out) needed[sa.y] = 1;
            if (da.z < rows_out) needed[sa.z] = 1;
            if (da.w < rows_out) needed[sa.w] = 1;
            if (db.x < rows_out) needed[sb.x] = 1;
            if (db.y < rows_out) needed[sb.y] = 1;
            if (db.z < rows_out) needed[sb.z] = 1;
            if (db.w < rows_out) needed[sb.w] = 1;
        }
    } else if (blockIdx.x < EP8 + SPLITB) {
        // x split phase (grid-stride over 1.6M f32x4), hi only
        int tid = (blockIdx.x - EP8) * 256 + t;
        const int total = NN * C / 4;
        for (int i = tid; i < total; i += SPLITB * 256) {
            f32x4 v = ((const f32x4*)x)[i];
            ushort h0 = bf16_rn(v.x), h1 = bf16_rn(v.y);
            ushort h2 = bf16_rn(v.z), h3 = bf16_rn(v.w);
            *(uint2*)(Ah + (size_t)i * 4) = make_uint2((unsigned)h0 | ((unsigned)h1 << 16),
                                                       (unsigned)h2 | ((unsigned)h3 << 16));
        }
    } else {
        // W split phase: 6 matrices x 16384 floats
        const float* Ws[6] = {W0, W1, W2, W3, W4, W5};
        int i = (blockIdx.x - EP8 - SPLITB) * 256 + t;
        int mat = i >> 12;
        f32x4 v = ((const f32x4*)Ws[mat])[i & 4095];
        ushort h0, h1, h2, h3, l0, l1, l2, l3;
        split_bf16(v.x, h0, l0);
        split_bf16(v.y, h1, l1);
        split_bf16(v.z, h2, l2);
        split_bf16(v.w, h3, l3);
        *(uint2*)(Wh + (size_t)i * 4) = make_uint2((unsigned)h0 | ((unsigned)h1 << 16),
                                                   (unsigned)h2 | ((unsigned)h3 << 16));
        *(uint2*)(Wl + (size_t)i * 4) = make_uint2((unsigned)l0 | ((unsigned)l1 << 16),
                                                   (unsigned)l2 | ((unsigned)l3 << 16));
    }
}

// ---- fused layer: mean-aggregate + dual GEMM + bias + PReLU ----
// out = prelu( mean_{e in col[r]}(Gsrc[e]) @ Wl.T + bl + X[r] @ Wr.T )
// The A-operand is gathered+meaned during LDS staging (no Gh/Gl round trip, no agg kernel).
// Thread (ar,aq) owns row ar's quarter: gathers d x 64B (bf16-hi), sums f32, mean, split->LDS.
// Identical math to the old agg+gemm pair (f32 sum reassociation only).
// X-side: pre-split (Xh,Xl) or raw f32 (Xf) split in-register (layer 0).
// list!=null: rows from list[]; outputs scattered to original rows.
// needed!=null: blocks >= gemmblocks run the needed->list compaction (rides L0 grid).

__global__ __launch_bounds__(256)
void fused_kernel(const ushort* __restrict__ Gsrc,
                  const int* __restrict__ deg, const int* __restrict__ col,
                  const ushort* __restrict__ Xh, const ushort* __restrict__ Xl,
                  const float* __restrict__ Xf,
                  const ushort* __restrict__ Wlh, const ushort* __restrict__ Wll,
                  const ushort* __restrict__ Wrh, const ushort* __restrict__ Wrl,
                  const float* __restrict__ bl, const float* __restrict__ slope,
                  const int* __restrict__ list, const int* __restrict__ countp,
                  float* __restrict__ outf, ushort* __restrict__ outh,
                  ushort* __restrict__ outl, int rows,
                  int gemmblocks, const int* __restrict__ needed,
                  int* __restrict__ wlist, int* __restrict__ wcnt, int rows_out) {
    if (needed && (int)blockIdx.x >= gemmblocks) {
        int i = ((int)blockIdx.x - gemmblocks) * 256 + threadIdx.x;
        if (i < NN && (i < rows_out || needed[i])) {
            int p = atomicAdd(wcnt, 1);
            wlist[p] = i;
        }
        return;
    }
    __shared__ ushort Ahi[64 * ASTRIDE];
    __shared__ ushort Alo[64 * ASTRIDE];
    int t = threadIdx.x;
    int lane = t & 63;
    int w = t >> 6;
    int l = lane & 15;
    int q = lane >> 4;
    int row0 = blockIdx.x * 64;
    int cnt = list ? min(*countp, rows) : rows;
    if (row0 >= cnt) return;

    f32x4 acc[4][2];
    #pragma unroll
    for (int mt = 0; mt < 4; ++mt)
        #pragma unroll
        for (int nt = 0; nt < 2; ++nt)
            acc[mt][nt] = (f32x4){0.f, 0.f, 0.f, 0.f};

    #pragma unroll
    for (int mat = 0; mat < 2; ++mat) {
        const ushort* WH = mat ? Wrh : Wlh;
        const ushort* WL = mat ? Wrl : Wll;

        bf16x8 bhi[2][4], blo[2][4];
        #pragma unroll
        for (int nt = 0; nt < 2; ++nt) {
            int n = w * 32 + nt * 16 + l;
            const ushort* wp = WH + (size_t)n * C + q * 8;
            const ushort* wq = WL + (size_t)n * C + q * 8;
            #pragma unroll
            for (int kb = 0; kb < 4; ++kb) {
                bhi[nt][kb] = *(const bf16x8*)(wp + kb * 32);
                blo[nt][kb] = *(const bf16x8*)(wq + kb * 32);
            }
        }

        __syncthreads();
        int ar = t >> 2;
        int aq = t & 3;
        int ridx = min(row0 + ar, cnt - 1);
        int r = list ? list[ridx] : ridx;
        ushort* dh = Ahi + ar * ASTRIDE + aq * 32;
        ushort* dl = Alo + ar * ASTRIDE + aq * 32;
        if (mat == 0) {
            // gather-mean staging: this thread sums its 32-channel quarter over d edges
            int d = min(deg[r], CAP);
            int base = r * CAP;
            float s[32];
            #pragma unroll
            for (int j = 0; j < 32; ++j) s[j] = 0.f;
#define ACC8(k, u, v) \
            s[(k)+0] += bf_lo((u).x) + bf_lo((v).x); s[(k)+1] += bf_hi((u).x) + bf_hi((v).x); \
            s[(k)+2] += bf_lo((u).y) + bf_lo((v).y); s[(k)+3] += bf_hi((u).y) + bf_hi((v).y); \
            s[(k)+4] += bf_lo((u).z) + bf_lo((v).z); s[(k)+5] += bf_hi((u).z) + bf_hi((v).z); \
            s[(k)+6] += bf_lo((u).w) + bf_lo((v).w); s[(k)+7] += bf_hi((u).w) + bf_hi((v).w);
#define ACC8S(k, u) \
            s[(k)+0] += bf_lo((u).x); s[(k)+1] += bf_hi((u).x); \
            s[(k)+2] += bf_lo((u).y); s[(k)+3] += bf_hi((u).y); \
            s[(k)+4] += bf_lo((u).z); s[(k)+5] += bf_hi((u).z); \
            s[(k)+6] += bf_lo((u).w); s[(k)+7] += bf_hi((u).w);
            int e = 0;
            for (; e + 1 < d; e += 2) {
                int2 c01 = *(const int2*)(col + base + e);
                const uint4* p0 = (const uint4*)Gsrc + (size_t)c01.x * 16 + aq * 4;
                const uint4* p1 = (const uint4*)Gsrc + (size_t)c01.y * 16 + aq * 4;
                uint4 a0 = p0[0], a1 = p0[1], a2 = p0[2], a3 = p0[3];
                uint4 b0 = p1[0], b1 = p1[1], b2 = p1[2], b3 = p1[3];
                ACC8(0, a0, b0) ACC8(8, a1, b1) ACC8(16, a2, b2) ACC8(24, a3, b3)
            }
            if (e < d) {
                int c0 = col[base + e];
                const uint4* p0 = (const uint4*)Gsrc + (size_t)c0 * 16 + aq * 4;
                uint4 a0 = p0[0], a1 = p0[1], a2 = p0[2], a3 = p0[3];
                ACC8S(0, a0) ACC8S(8, a1) ACC8S(16, a2) ACC8S(24, a3)
            }
#undef ACC8
#undef ACC8S
            float inv = 1.0f / (float)max(d, 1);
            #pragma unroll
            for (int i = 0; i < 4; ++i) {
                ushort h[8], o[8];
                #pragma unroll
                for (int j = 0; j < 8; ++j) split_bf16(s[i * 8 + j] * inv, h[j], o[j]);
                *(uint4*)(dh + i * 8) = make_uint4((unsigned)h[0] | ((unsigned)h[1] << 16),
                                                   (unsigned)h[2] | ((unsigned)h[3] << 16),
                                                   (unsigned)h[4] | ((unsigned)h[5] << 16),
                                                   (unsigned)h[6] | ((unsigned)h[7] << 16));
                *(uint4*)(dl + i * 8) = make_uint4((unsigned)o[0] | ((unsigned)o[1] << 16),
                                                   (unsigned)o[2] | ((unsigned)o[3] << 16),
                                                   (unsigned)o[4] | ((unsigned)o[5] << 16),
                                                   (unsigned)o[6] | ((unsigned)o[7] << 16));
            }
        } else if (Xf) {
            const float* px = Xf + (size_t)r * C + aq * 32;
            #pragma unroll
            for (int i = 0; i < 8; ++i) {
                f32x4 v = *(const f32x4*)(px + i * 4);
                ushort h0, h1, h2, h3, l0, l1, l2, l3;
                split_bf16(v.x, h0, l0);
                split_bf16(v.y, h1, l1);
                split_bf16(v.z, h2, l2);
                split_bf16(v.w, h3, l3);
                *(uint2*)(dh + i * 4) = make_uint2((unsigned)h0 | ((unsigned)h1 << 16),
                                                   (unsigned)h2 | ((unsigned)h3 << 16));
                *(uint2*)(dl + i * 4) = make_uint2((unsigned)l0 | ((unsigned)l1 << 16),
                                                   (unsigned)l2 | ((unsigned)l3 << 16));
            }
        } else {
            const ushort* ph = Xh + (size_t)r * C + aq * 32;
            const ushort* pl = Xl + (size_t)r * C + aq * 32;
            #pragma unroll
            for (int i = 0; i < 4; ++i) {
                *(uint4*)(dh + i * 8) = *(const uint4*)(ph + i * 8);
                *(uint4*)(dl + i * 8) = *(const uint4*)(pl + i * 8);
            }
        }
        __syncthreads();

        #pragma unroll
        for (int kb = 0; kb < 4; ++kb) {
            #pragma unroll
            for (int mt = 0; mt < 4; ++mt) {
                int off = (mt * 16 + l) * ASTRIDE + kb * 32 + q * 8;
                bf16x8 ahi = *(const bf16x8*)(Ahi + off);
                bf16x8 alo = *(const bf16x8*)(Alo + off);
                #pragma unroll
                for (int nt = 0; nt < 2; ++nt) {
                    acc[mt][nt] = __builtin_amdgcn_mfma_f32_16x16x32_bf16(ahi, bhi[nt][kb], acc[mt][nt], 0, 0, 0);
                    acc[mt][nt] = __builtin_amdgcn_mfma_f32_16x16x32_bf16(alo, bhi[nt][kb], acc[mt][nt], 0, 0, 0);
                    acc[mt][nt] = __builtin_amdgcn_mfma_f32_16x16x32_bf16(ahi, blo[nt][kb], acc[mt][nt], 0, 0, 0);
                }
            }
        }
    }

    #pragma unroll
    for (int nt = 0; nt < 2; ++nt) {
        int n = w * 32 + nt * 16 + l;
        float b = bl[n], s = slope[n];
        #pragma unroll
        for (int mt = 0; mt < 4; ++mt) {
            #pragma unroll
            for (int rg = 0; rg < 4; ++rg) {
                int ridx = row0 + mt * 16 + q * 4 + rg;
                if (ridx < cnt) {
                    int r = list ? list[ridx] : ridx;
                    float v = acc[mt][nt][rg] + b;
                    v = v > 0.f ? v : s * v;
                    if (outf) {
                        outf[(size_t)r * C + n] = v;
                    } else {
                        ushort hh, ll;
                        split_bf16(v, hh, ll);
                        outh[(size_t)r * C + n] = hh;
                        outl[(size_t)r * C + n] = ll;
                    }
                }
            }
        }
    }
}

// ---------------- launch ----------------

extern "C" void kernel_launch(void* const* d_in, const int* in_sizes, int n_in,
                              void* d_out, int out_size, void* d_ws, size_t ws_size,
                              hipStream_t stream) {
    const float* x   = (const float*)d_in[0];
    const int*   src = (const int*)d_in[1];
    const int*   dst = src + NE;
    const float* Wl[3] = {(const float*)d_in[3], (const float*)d_in[7],  (const float*)d_in[11]};
    const float* bl[3] = {(const float*)d_in[4], (const float*)d_in[8],  (const float*)d_in[12]};
    const float* Wr[3] = {(const float*)d_in[5], (const float*)d_in[9],  (const float*)d_in[13]};
    const float* sl[3] = {(const float*)d_in[6], (const float*)d_in[10], (const float*)d_in[14]};

    int*   deg     = (int*)d_ws;             // 50016
    int*   needed  = deg + 50016;            // 50016
    int*   cnt     = needed + 50016;         // 16 (one used)
    int*   col     = cnt + 16;               // NN*CAP = 3.2M ints
    int*   list    = col + NN * CAP;         // 50016
    ushort* Whs    = (ushort*)(list + 50016);    // 6*16384 pre-split W hi
    ushort* Wls    = Whs + 6 * 16384;        // 6*16384 pre-split W lo
    ushort* Ah     = Wls + 6 * 16384;        // x-hi from prep; layer-1 out hi
    ushort* Al     = Ah + (size_t)NN * C;    // layer-1 out lo
    ushort* Bh     = Al + (size_t)NN * C;    // layer-0 out hi
    ushort* Bl     = Bh + (size_t)NN * C;    // layer-0 out lo

    int rows_out = out_size / C;             // 1024
    int gb = (NN + 63) / 64;                 // 782 gemm blocks for full-node layers

    // zero deg + needed + cnt (contiguous)
    hipMemsetAsync(deg, 0, (2 * 50016 + 16) * sizeof(int), stream);

    // W order: Wl0, Wr0, Wl1, Wr1, Wl2, Wr2
    prep_kernel<<<EP8 + SPLITB + WB, 256, 0, stream>>>(
        src, dst, x, Wl[0], Wr[0], Wl[1], Wr[1], Wl[2], Wr[2],
        deg, col, Ah, Whs, Wls, needed, rows_out);

    // layer 0 (full): gather Ah (x-hi), X-side = x f32; -> B. Compaction rides tail blocks.
    fused_kernel<<<gb + CB, 256, 0, stream>>>(Ah, deg, col, nullptr, nullptr, x,
                                              Whs + 0 * 16384, Wls + 0 * 16384,
                                              Whs + 1 * 16384, Wls + 1 * 16384,
                                              bl[0], sl[0], nullptr, nullptr,
                                              nullptr, Bh, Bl, NN,
                                              gb, needed, list, cnt, rows_out);

    // layer 1 (pruned to list): gather Bh, X-side = Bh/Bl; -> A (scattered at original rows)
    fused_kernel<<<gb, 256, 0, stream>>>(Bh, deg, col, Bh, Bl, nullptr,
                                         Whs + 2 * 16384, Wls + 2 * 16384,
                                         Whs + 3 * 16384, Wls + 3 * 16384,
                                         bl[1], sl[1], list, cnt,
                                         nullptr, Ah, Al, NN,
                                         gb, nullptr, nullptr, nullptr, rows_out);

    // layer 2 (first rows_out nodes): gather Ah, X-side = Ah/Al; -> d_out (f32)
    fused_kernel<<<(rows_out + 63) / 64, 256, 0, stream>>>(Ah, deg, col, Ah, Al, nullptr,
                                                           Whs + 4 * 16384, Wls + 4 * 16384,
                                                           Whs + 5 * 16384, Wls + 5 * 16384,
                                                           bl[2], sl[2], nullptr, nullptr,
                                                           (float*)d_out, nullptr, nullptr,
                                                           rows_out,
                                                           (rows_out + 63) / 64, nullptr,
                                                           nullptr, nullptr, rows_out);
}

// Round 6
// 274.960 us; speedup vs baseline: 1.0524x; 1.0524x over previous
//
#include <hip/hip_runtime.h>

#define NN 50000
#define NE 800000
#define C 128
#define CAP 64                           // fixed edge capacity per node (P(deg>=64) ~ 4e-18)
#define DEGS 16                          // deg counter stride (ints): 1 counter per 64B line
#define EP8 ((NE / 8 + 255) / 256)       // 391 edge-place blocks (8 edges/thread)
#define SPLITB 1563                      // x-split blocks
#define WB 96                            // W-split blocks: 6*16384 floats / 4 / 256
#define CB  ((NN + 255) / 256)           // 196 compact blocks (appended to agg0 grid)
#define AGG0B ((NN + 3) / 4)             // 12500 agg blocks for full-node layers
#define ASTRIDE 136                      // bf16 elems per LDS A row

typedef __attribute__((ext_vector_type(8))) short bf16x8;
typedef __attribute__((ext_vector_type(4))) float f32x4;
typedef unsigned short ushort;

__device__ inline ushort bf16_rn(float f) {
    unsigned u = __builtin_bit_cast(unsigned, f);
    u += 0x7FFF + ((u >> 16) & 1);
    return (ushort)(u >> 16);
}
__device__ inline void split_bf16(float f, ushort& hi, ushort& lo) {
    hi = bf16_rn(f);
    float hif = __builtin_bit_cast(float, (unsigned)hi << 16);
    lo = bf16_rn(f - hif);               // residual, ~2^-17 rel total
}
__device__ inline float bf_lo(unsigned u) { return __builtin_bit_cast(float, u << 16); }
__device__ inline float bf_hi(unsigned u) { return __builtin_bit_cast(float, u & 0xFFFF0000u); }

// ---- fused prep: edge place (count+scatter+mark, 8 edges/thread) + split x (hi only) + split W ----
// deg counters padded to one 64B line each (DEGS=16): 800k atomics over 50k lines = 16/line
// instead of 256/line -> breaks L2 same-line atomic serialization (theory of r6).
// Returning atomicAdd gives the bucket slot directly -> no pos array, no fill kernel.

__global__ __launch_bounds__(256)
void prep_kernel(const int* __restrict__ src, const int* __restrict__ dst,
                 const float* __restrict__ x,
                 const float* __restrict__ W0, const float* __restrict__ W1,
                 const float* __restrict__ W2, const float* __restrict__ W3,
                 const float* __restrict__ W4, const float* __restrict__ W5,
                 int* __restrict__ deg, int* __restrict__ col,
                 ushort* __restrict__ Ah,
                 ushort* __restrict__ Wh, ushort* __restrict__ Wl,
                 int* __restrict__ needed, int rows_out) {
    int t = threadIdx.x;
    if (blockIdx.x < EP8) {
        int e0 = (blockIdx.x * 256 + t) * 8;
        if (e0 < NE) {
            int4 da = *(const int4*)(dst + e0);
            int4 db = *(const int4*)(dst + e0 + 4);
            int4 sa = *(const int4*)(src + e0);
            int4 sb = *(const int4*)(src + e0 + 4);
            int p0 = atomicAdd(&deg[da.x * DEGS], 1);
            int p1 = atomicAdd(&deg[da.y * DEGS], 1);
            int p2 = atomicAdd(&deg[da.z * DEGS], 1);
            int p3 = atomicAdd(&deg[da.w * DEGS], 1);
            int p4 = atomicAdd(&deg[db.x * DEGS], 1);
            int p5 = atomicAdd(&deg[db.y * DEGS], 1);
            int p6 = atomicAdd(&deg[db.z * DEGS], 1);
            int p7 = atomicAdd(&deg[db.w * DEGS], 1);
            if (p0 < CAP) col[da.x * CAP + p0] = sa.x;
            if (p1 < CAP) col[da.y * CAP + p1] = sa.y;
            if (p2 < CAP) col[da.z * CAP + p2] = sa.z;
            if (p3 < CAP) col[da.w * CAP + p3] = sa.w;
            if (p4 < CAP) col[db.x * CAP + p4] = sb.x;
            if (p5 < CAP) col[db.y * CAP + p5] = sb.y;
            if (p6 < CAP) col[db.z * CAP + p6] = sb.z;
            if (p7 < CAP) col[db.w * CAP + p7] = sb.w;
            if (da.x < rows_out) needed[sa.x] = 1;
            if (da.y < rows_out) needed[sa.y] = 1;
            if (da.z < rows_out) needed[sa.z] = 1;
            if (da.w < rows_out) needed[sa.w] = 1;
            if (db.x < rows_out) needed[sb.x] = 1;
            if (db.y < rows_out) needed[sb.y] = 1;
            if (db.z < rows_out) needed[sb.z] = 1;
            if (db.w < rows_out) needed[sb.w] = 1;
        }
    } else if (blockIdx.x < EP8 + SPLITB) {
        // x split phase (grid-stride over 1.6M f32x4), hi only
        int tid = (blockIdx.x - EP8) * 256 + t;
        const int total = NN * C / 4;
        for (int i = tid; i < total; i += SPLITB * 256) {
            f32x4 v = ((const f32x4*)x)[i];
            ushort h0 = bf16_rn(v.x), h1 = bf16_rn(v.y);
            ushort h2 = bf16_rn(v.z), h3 = bf16_rn(v.w);
            *(uint2*)(Ah + (size_t)i * 4) = make_uint2((unsigned)h0 | ((unsigned)h1 << 16),
                                                       (unsigned)h2 | ((unsigned)h3 << 16));
        }
    } else {
        // W split phase: 6 matrices x 16384 floats
        const float* Ws[6] = {W0, W1, W2, W3, W4, W5};
        int i = (blockIdx.x - EP8 - SPLITB) * 256 + t;
        int mat = i >> 12;
        f32x4 v = ((const f32x4*)Ws[mat])[i & 4095];
        ushort h0, h1, h2, h3, l0, l1, l2, l3;
        split_bf16(v.x, h0, l0);
        split_bf16(v.y, h1, l1);
        split_bf16(v.z, h2, l2);
        split_bf16(v.w, h3, l3);
        *(uint2*)(Wh + (size_t)i * 4) = make_uint2((unsigned)h0 | ((unsigned)h1 << 16),
                                                   (unsigned)h2 | ((unsigned)h3 << 16));
        *(uint2*)(Wl + (size_t)i * 4) = make_uint2((unsigned)l0 | ((unsigned)l1 << 16),
                                                   (unsigned)l2 | ((unsigned)l3 << 16));
    }
}

// ---- mean aggregation: one wave per (listed) node, 4 edge-rows per VMEM instr ----
// Row = 256 B of bf16-hi. 16 lanes x uint4 per edge-row; quad = lane>>4 picks edge.
// Direct col loads (proven addressing); 16-edge unroll keeps 4 row-gathers in flight.
// needed!=null: tail blocks run needed->list compaction.

__global__ __launch_bounds__(256)
void agg_kernel(const ushort* __restrict__ xh, const int* __restrict__ deg,
                const int* __restrict__ col,
                const int* __restrict__ list, const int* __restrict__ countp,
                ushort* __restrict__ aggh, ushort* __restrict__ aggl, int nodes,
                int aggblocks, const int* __restrict__ needed,
                int* __restrict__ wlist, int* __restrict__ wcnt, int rows_out) {
    if (needed && blockIdx.x >= aggblocks) {
        int i = (blockIdx.x - aggblocks) * 256 + threadIdx.x;
        if (i < NN && (i < rows_out || needed[i])) {
            int p = atomicAdd(wcnt, 1);
            wlist[p] = i;
        }
        return;
    }
    int i = (blockIdx.x * blockDim.x + threadIdx.x) >> 6;
    int lane = threadIdx.x & 63;
    int cnt = list ? *countp : nodes;
    if (i >= cnt) return;
    int node = list ? list[i] : i;
    int quad = lane >> 4;
    int ql   = lane & 15;
    int d = min(deg[node * DEGS], CAP);
    int start = node * CAP;
    int end = start + d;
    const uint4* xr = (const uint4*)xh;
    float a0=0,a1=0,a2=0,a3=0,a4=0,a5=0,a6=0,a7=0;
    int e = start;
    for (; e + 15 < end; e += 16) {
        int i0 = col[e + quad];
        int i1 = col[e + 4 + quad];
        int i2 = col[e + 8 + quad];
        int i3 = col[e + 12 + quad];
        uint4 u0 = xr[(size_t)i0 * 16 + ql];
        uint4 u1 = xr[(size_t)i1 * 16 + ql];
        uint4 u2 = xr[(size_t)i2 * 16 + ql];
        uint4 u3 = xr[(size_t)i3 * 16 + ql];
        a0 += (bf_lo(u0.x) + bf_lo(u1.x)) + (bf_lo(u2.x) + bf_lo(u3.x));
        a1 += (bf_hi(u0.x) + bf_hi(u1.x)) + (bf_hi(u2.x) + bf_hi(u3.x));
        a2 += (bf_lo(u0.y) + bf_lo(u1.y)) + (bf_lo(u2.y) + bf_lo(u3.y));
        a3 += (bf_hi(u0.y) + bf_hi(u1.y)) + (bf_hi(u2.y) + bf_hi(u3.y));
        a4 += (bf_lo(u0.z) + bf_lo(u1.z)) + (bf_lo(u2.z) + bf_lo(u3.z));
        a5 += (bf_hi(u0.z) + bf_hi(u1.z)) + (bf_hi(u2.z) + bf_hi(u3.z));
        a6 += (bf_lo(u0.w) + bf_lo(u1.w)) + (bf_lo(u2.w) + bf_lo(u3.w));
        a7 += (bf_hi(u0.w) + bf_hi(u1.w)) + (bf_hi(u2.w) + bf_hi(u3.w));
    }
    for (; e + 7 < end; e += 8) {
        int i0 = col[e + quad];
        int i1 = col[e + 4 + quad];
        uint4 u0 = xr[(size_t)i0 * 16 + ql];
        uint4 u1 = xr[(size_t)i1 * 16 + ql];
        a0 += bf_lo(u0.x) + bf_lo(u1.x); a1 += bf_hi(u0.x) + bf_hi(u1.x);
        a2 += bf_lo(u0.y) + bf_lo(u1.y); a3 += bf_hi(u0.y) + bf_hi(u1.y);
        a4 += bf_lo(u0.z) + bf_lo(u1.z); a5 += bf_hi(u0.z) + bf_hi(u1.z);
        a6 += bf_lo(u0.w) + bf_lo(u1.w); a7 += bf_hi(u0.w) + bf_hi(u1.w);
    }
    for (; e + 3 < end; e += 4) {
        uint4 u = xr[(size_t)col[e + quad] * 16 + ql];
        a0 += bf_lo(u.x); a1 += bf_hi(u.x);
        a2 += bf_lo(u.y); a3 += bf_hi(u.y);
        a4 += bf_lo(u.z); a5 += bf_hi(u.z);
        a6 += bf_lo(u.w); a7 += bf_hi(u.w);
    }
    int rem = end - e;
    if (quad < rem) {
        uint4 u = xr[(size_t)col[e + quad] * 16 + ql];
        a0 += bf_lo(u.x); a1 += bf_hi(u.x);
        a2 += bf_lo(u.y); a3 += bf_hi(u.y);
        a4 += bf_lo(u.z); a5 += bf_hi(u.z);
        a6 += bf_lo(u.w); a7 += bf_hi(u.w);
    }
    a0 += __shfl_xor(a0, 16, 64); a0 += __shfl_xor(a0, 32, 64);
    a1 += __shfl_xor(a1, 16, 64); a1 += __shfl_xor(a1, 32, 64);
    a2 += __shfl_xor(a2, 16, 64); a2 += __shfl_xor(a2, 32, 64);
    a3 += __shfl_xor(a3, 16, 64); a3 += __shfl_xor(a3, 32, 64);
    a4 += __shfl_xor(a4, 16, 64); a4 += __shfl_xor(a4, 32, 64);
    a5 += __shfl_xor(a5, 16, 64); a5 += __shfl_xor(a5, 32, 64);
    a6 += __shfl_xor(a6, 16, 64); a6 += __shfl_xor(a6, 32, 64);
    a7 += __shfl_xor(a7, 16, 64); a7 += __shfl_xor(a7, 32, 64);
    if (quad == 0) {
        float inv = 1.0f / (float)max(d, 1);
        float m[8] = {a0*inv, a1*inv, a2*inv, a3*inv, a4*inv, a5*inv, a6*inv, a7*inv};
        ushort h[8], o[8];
        #pragma unroll
        for (int j = 0; j < 8; ++j) split_bf16(m[j], h[j], o[j]);
        size_t off = (size_t)node * C + ql * 8;
        *(uint4*)(aggh + off) = make_uint4((unsigned)h[0] | ((unsigned)h[1] << 16),
                                           (unsigned)h[2] | ((unsigned)h[3] << 16),
                                           (unsigned)h[4] | ((unsigned)h[5] << 16),
                                           (unsigned)h[6] | ((unsigned)h[7] << 16));
        *(uint4*)(aggl + off) = make_uint4((unsigned)o[0] | ((unsigned)o[1] << 16),
                                           (unsigned)o[2] | ((unsigned)o[3] << 16),
                                           (unsigned)o[4] | ((unsigned)o[5] << 16),
                                           (unsigned)o[6] | ((unsigned)o[7] << 16));
    }
}

// ---- fused dual GEMM + bias + PReLU via split-bf16 MFMA ----
// out = prelu( A@Wl.T + bl + X@Wr.T ); A always pre-split hi/lo.
// X-side: either pre-split (Xh,Xl) or raw f32 (Xf != null, layer 0) split in-register.
// list!=null: rows from list[]; output scattered to original rows.

__global__ __launch_bounds__(256, 4)
void gemm_kernel(const ushort* __restrict__ Ah, const ushort* __restrict__ Al,
                 const ushort* __restrict__ Xh, const ushort* __restrict__ Xl,
                 const float* __restrict__ Xf,
                 const ushort* __restrict__ Wlh, const ushort* __restrict__ Wll,
                 const ushort* __restrict__ Wrh, const ushort* __restrict__ Wrl,
                 const float* __restrict__ bl, const float* __restrict__ slope,
                 const int* __restrict__ list, const int* __restrict__ countp,
                 float* __restrict__ outf, ushort* __restrict__ outh,
                 ushort* __restrict__ outl, int rows) {
    __shared__ ushort Ahi[64 * ASTRIDE];
    __shared__ ushort Alo[64 * ASTRIDE];
    int t = threadIdx.x;
    int lane = t & 63;
    int w = t >> 6;
    int l = lane & 15;
    int q = lane >> 4;
    int row0 = blockIdx.x * 64;
    int cnt = list ? min(*countp, rows) : rows;
    if (row0 >= cnt) return;

    f32x4 acc[4][2];
    #pragma unroll
    for (int mt = 0; mt < 4; ++mt)
        #pragma unroll
        for (int nt = 0; nt < 2; ++nt)
            acc[mt][nt] = (f32x4){0.f, 0.f, 0.f, 0.f};

    #pragma unroll
    for (int mat = 0; mat < 2; ++mat) {
        const ushort* WH = mat ? Wrh : Wlh;
        const ushort* WL = mat ? Wrl : Wll;
        const ushort* Ph = mat ? Xh : Ah;
        const ushort* Pl = mat ? Xl : Al;

        bf16x8 bhi[2][4], blo[2][4];
        #pragma unroll
        for (int nt = 0; nt < 2; ++nt) {
            int n = w * 32 + nt * 16 + l;
            const ushort* wp = WH + (size_t)n * C + q * 8;
            const ushort* wq = WL + (size_t)n * C + q * 8;
            #pragma unroll
            for (int kb = 0; kb < 4; ++kb) {
                bhi[nt][kb] = *(const bf16x8*)(wp + kb * 32);
                blo[nt][kb] = *(const bf16x8*)(wq + kb * 32);
            }
        }

        __syncthreads();
        int ar = t >> 2;
        int aq = t & 3;
        int ridx = min(row0 + ar, cnt - 1);
        int r = list ? list[ridx] : ridx;
        ushort* dh = Ahi + ar * ASTRIDE + aq * 32;
        ushort* dl = Alo + ar * ASTRIDE + aq * 32;
        if (mat == 1 && Xf) {
            const float* px = Xf + (size_t)r * C + aq * 32;
            #pragma unroll
            for (int i = 0; i < 8; ++i) {
                f32x4 v = *(const f32x4*)(px + i * 4);
                ushort h0, h1, h2, h3, l0, l1, l2, l3;
                split_bf16(v.x, h0, l0);
                split_bf16(v.y, h1, l1);
                split_bf16(v.z, h2, l2);
                split_bf16(v.w, h3, l3);
                *(uint2*)(dh + i * 4) = make_uint2((unsigned)h0 | ((unsigned)h1 << 16),
                                                   (unsigned)h2 | ((unsigned)h3 << 16));
                *(uint2*)(dl + i * 4) = make_uint2((unsigned)l0 | ((unsigned)l1 << 16),
                                                   (unsigned)l2 | ((unsigned)l3 << 16));
            }
        } else {
            const ushort* ph = Ph + (size_t)r * C + aq * 32;
            const ushort* pl = Pl + (size_t)r * C + aq * 32;
            #pragma unroll
            for (int i = 0; i < 4; ++i) {
                *(uint4*)(dh + i * 8) = *(const uint4*)(ph + i * 8);
                *(uint4*)(dl + i * 8) = *(const uint4*)(pl + i * 8);
            }
        }
        __syncthreads();

        #pragma unroll
        for (int kb = 0; kb < 4; ++kb) {
            #pragma unroll
            for (int mt = 0; mt < 4; ++mt) {
                int off = (mt * 16 + l) * ASTRIDE + kb * 32 + q * 8;
                bf16x8 ahi = *(const bf16x8*)(Ahi + off);
                bf16x8 alo = *(const bf16x8*)(Alo + off);
                #pragma unroll
                for (int nt = 0; nt < 2; ++nt) {
                    acc[mt][nt] = __builtin_amdgcn_mfma_f32_16x16x32_bf16(ahi, bhi[nt][kb], acc[mt][nt], 0, 0, 0);
                    acc[mt][nt] = __builtin_amdgcn_mfma_f32_16x16x32_bf16(alo, bhi[nt][kb], acc[mt][nt], 0, 0, 0);
                    acc[mt][nt] = __builtin_amdgcn_mfma_f32_16x16x32_bf16(ahi, blo[nt][kb], acc[mt][nt], 0, 0, 0);
                }
            }
        }
    }

    #pragma unroll
    for (int nt = 0; nt < 2; ++nt) {
        int n = w * 32 + nt * 16 + l;
        float b = bl[n], s = slope[n];
        #pragma unroll
        for (int mt = 0; mt < 4; ++mt) {
            #pragma unroll
            for (int rg = 0; rg < 4; ++rg) {
                int ridx = row0 + mt * 16 + q * 4 + rg;
                if (ridx < cnt) {
                    int r = list ? list[ridx] : ridx;
                    float v = acc[mt][nt][rg] + b;
                    v = v > 0.f ? v : s * v;
                    if (outf) {
                        outf[(size_t)r * C + n] = v;
                    } else {
                        ushort hh, ll;
                        split_bf16(v, hh, ll);
                        outh[(size_t)r * C + n] = hh;
                        outl[(size_t)r * C + n] = ll;
                    }
                }
            }
        }
    }
}

// ---------------- launch ----------------

extern "C" void kernel_launch(void* const* d_in, const int* in_sizes, int n_in,
                              void* d_out, int out_size, void* d_ws, size_t ws_size,
                              hipStream_t stream) {
    const float* x   = (const float*)d_in[0];
    const int*   src = (const int*)d_in[1];
    const int*   dst = src + NE;
    const float* Wl[3] = {(const float*)d_in[3], (const float*)d_in[7],  (const float*)d_in[11]};
    const float* bl[3] = {(const float*)d_in[4], (const float*)d_in[8],  (const float*)d_in[12]};
    const float* Wr[3] = {(const float*)d_in[5], (const float*)d_in[9],  (const float*)d_in[13]};
    const float* sl[3] = {(const float*)d_in[6], (const float*)d_in[10], (const float*)d_in[14]};

    int*   deg     = (int*)d_ws;             // NN*DEGS = 800000 ints (1 counter per 64B line)
    int*   needed  = deg + NN * DEGS;        // 50016
    int*   cnt     = needed + 50016;         // 16 (one used)
    int*   col     = cnt + 16;               // NN*CAP = 3.2M ints
    int*   list    = col + NN * CAP;         // 50016
    ushort* Whs    = (ushort*)(list + 50016);    // 6*16384 pre-split W hi
    ushort* Wls    = Whs + 6 * 16384;        // 6*16384 pre-split W lo
    ushort* Gh     = Wls + 6 * 16384;        // agg hi, NN*C
    ushort* Gl     = Gh + (size_t)NN * C;    // agg lo
    ushort* Ah     = Gl + (size_t)NN * C;    // ping hi (x-hi from prep; layer-1 out)
    ushort* Al     = Ah + (size_t)NN * C;    // ping lo (layer-1 out only)
    ushort* Bh     = Al + (size_t)NN * C;    // pong hi
    ushort* Bl     = Bh + (size_t)NN * C;    // pong lo

    int rows_out = out_size / C;             // 1024

    // zero deg (padded) + needed + cnt (contiguous)
    hipMemsetAsync(deg, 0, (NN * DEGS + 50016 + 16) * sizeof(int), stream);

    // W order: Wl0, Wr0, Wl1, Wr1, Wl2, Wr2
    prep_kernel<<<EP8 + SPLITB + WB, 256, 0, stream>>>(
        src, dst, x, Wl[0], Wr[0], Wl[1], Wr[1], Wl[2], Wr[2],
        deg, col, Ah, Whs, Wls, needed, rows_out);

    // layer 0 (full): x -> B; compaction rides the tail blocks of agg0
    agg_kernel<<<AGG0B + CB, 256, 0, stream>>>(Ah, deg, col, nullptr, nullptr, Gh, Gl, NN,
                                               AGG0B, needed, list, cnt, rows_out);
    gemm_kernel<<<(NN + 63) / 64, 256, 0, stream>>>(Gh, Gl, nullptr, nullptr, x,
                                                    Whs + 0 * 16384, Wls + 0 * 16384,
                                                    Whs + 1 * 16384, Wls + 1 * 16384,
                                                    bl[0], sl[0], nullptr, nullptr,
                                                    nullptr, Bh, Bl, NN);

    // layer 1 (pruned to needed list): B -> A (scattered at original rows)
    agg_kernel<<<AGG0B, 256, 0, stream>>>(Bh, deg, col, list, cnt, Gh, Gl, NN,
                                          AGG0B, nullptr, nullptr, nullptr, rows_out);
    gemm_kernel<<<(NN + 63) / 64, 256, 0, stream>>>(Gh, Gl, Bh, Bl, nullptr,
                                                    Whs + 2 * 16384, Wls + 2 * 16384,
                                                    Whs + 3 * 16384, Wls + 3 * 16384,
                                                    bl[1], sl[1], list, cnt,
                                                    nullptr, Ah, Al, NN);

    // layer 2 (first rows_out nodes): A -> d_out
    agg_kernel<<<(rows_out + 3) / 4, 256, 0, stream>>>(Ah, deg, col, nullptr, nullptr,
                                                       Gh, Gl, rows_out,
                                                       (rows_out + 3) / 4, nullptr,
                                                       nullptr, nullptr, rows_out);
    gemm_kernel<<<(rows_out + 63) / 64, 256, 0, stream>>>(Gh, Gl, Ah, Al, nullptr,
                                                          Whs + 4 * 16384, Wls + 4 * 16384,
                                                          Whs + 5 * 16384, Wls + 5 * 16384,
                                                          bl[2], sl[2], nullptr, nullptr,
                                                          (float*)d_out, nullptr, nullptr,
                                                          rows_out);
}

// Round 7
// 272.917 us; speedup vs baseline: 1.0603x; 1.0075x over previous
//
#include <hip/hip_runtime.h>

#define NN 50000
#define NE 800000
#define C 128
#define CAP 64                           // fixed edge capacity per node (P(deg>=64) ~ 4e-18)
#define DEGS 16                          // deg counter stride (ints): 1 counter per 64B line
#define EP16 ((NE / 16 + 255) / 256)     // 196 edge-place blocks (16 edges/thread)
#define SPLITB 1563                      // x-split blocks
#define WB 96                            // W-split blocks: 6*16384 floats / 4 / 256
#define CB  ((NN + 255) / 256)           // 196 compact blocks (appended to agg0 grid)
#define AGG0B ((NN + 3) / 4)             // 12500 agg blocks for full-node layers
#define ASTRIDE 136                      // bf16 elems per LDS A row

typedef __attribute__((ext_vector_type(8))) short bf16x8;
typedef __attribute__((ext_vector_type(4))) float f32x4;
typedef unsigned short ushort;

__device__ inline ushort bf16_rn(float f) {
    unsigned u = __builtin_bit_cast(unsigned, f);
    u += 0x7FFF + ((u >> 16) & 1);
    return (ushort)(u >> 16);
}
__device__ inline void split_bf16(float f, ushort& hi, ushort& lo) {
    hi = bf16_rn(f);
    float hif = __builtin_bit_cast(float, (unsigned)hi << 16);
    lo = bf16_rn(f - hif);               // residual, ~2^-17 rel total
}
__device__ inline float bf_lo(unsigned u) { return __builtin_bit_cast(float, u << 16); }
__device__ inline float bf_hi(unsigned u) { return __builtin_bit_cast(float, u & 0xFFFF0000u); }

// ---- fused prep: edge place (count+scatter+mark, 16 edges/thread) + split x (hi only) + split W ----
// deg counters line-padded (DEGS=16) -> no false sharing (r6: -11us).
// 16 edges/thread continues the measured ILP trend (2/thr=71, 4/thr=63.5, 8/thr=53).

__global__ __launch_bounds__(256)
void prep_kernel(const int* __restrict__ src, const int* __restrict__ dst,
                 const float* __restrict__ x,
                 const float* __restrict__ W0, const float* __restrict__ W1,
                 const float* __restrict__ W2, const float* __restrict__ W3,
                 const float* __restrict__ W4, const float* __restrict__ W5,
                 int* __restrict__ deg, int* __restrict__ col,
                 ushort* __restrict__ Ah,
                 ushort* __restrict__ Wh, ushort* __restrict__ Wl,
                 int* __restrict__ needed, int rows_out) {
    int t = threadIdx.x;
    if (blockIdx.x < EP16) {
        int e0 = (blockIdx.x * 256 + t) * 16;
        if (e0 < NE) {
            #pragma unroll
            for (int g = 0; g < 4; ++g) {
                int4 d4 = *(const int4*)(dst + e0 + g * 4);
                int4 s4 = *(const int4*)(src + e0 + g * 4);
                int p0 = atomicAdd(&deg[d4.x * DEGS], 1);
                int p1 = atomicAdd(&deg[d4.y * DEGS], 1);
                int p2 = atomicAdd(&deg[d4.z * DEGS], 1);
                int p3 = atomicAdd(&deg[d4.w * DEGS], 1);
                if (p0 < CAP) col[d4.x * CAP + p0] = s4.x;
                if (p1 < CAP) col[d4.y * CAP + p1] = s4.y;
                if (p2 < CAP) col[d4.z * CAP + p2] = s4.z;
                if (p3 < CAP) col[d4.w * CAP + p3] = s4.w;
                if (d4.x < rows_out) needed[s4.x] = 1;
                if (d4.y < rows_out) needed[s4.y] = 1;
                if (d4.z < rows_out) needed[s4.z] = 1;
                if (d4.w < rows_out) needed[s4.w] = 1;
            }
        }
    } else if (blockIdx.x < EP16 + SPLITB) {
        // x split phase (grid-stride over 1.6M f32x4), hi only
        int tid = (blockIdx.x - EP16) * 256 + t;
        const int total = NN * C / 4;
        for (int i = tid; i < total; i += SPLITB * 256) {
            f32x4 v = ((const f32x4*)x)[i];
            ushort h0 = bf16_rn(v.x), h1 = bf16_rn(v.y);
            ushort h2 = bf16_rn(v.z), h3 = bf16_rn(v.w);
            *(uint2*)(Ah + (size_t)i * 4) = make_uint2((unsigned)h0 | ((unsigned)h1 << 16),
                                                       (unsigned)h2 | ((unsigned)h3 << 16));
        }
    } else {
        // W split phase: 6 matrices x 16384 floats
        const float* Ws[6] = {W0, W1, W2, W3, W4, W5};
        int i = (blockIdx.x - EP16 - SPLITB) * 256 + t;
        int mat = i >> 12;
        f32x4 v = ((const f32x4*)Ws[mat])[i & 4095];
        ushort h0, h1, h2, h3, l0, l1, l2, l3;
        split_bf16(v.x, h0, l0);
        split_bf16(v.y, h1, l1);
        split_bf16(v.z, h2, l2);
        split_bf16(v.w, h3, l3);
        *(uint2*)(Wh + (size_t)i * 4) = make_uint2((unsigned)h0 | ((unsigned)h1 << 16),
                                                   (unsigned)h2 | ((unsigned)h3 << 16));
        *(uint2*)(Wl + (size_t)i * 4) = make_uint2((unsigned)l0 | ((unsigned)l1 << 16),
                                                   (unsigned)l2 | ((unsigned)l3 << 16));
    }
}

// ---- mean aggregation: one wave per (listed) node; OUTPUT bf16-hi ONLY (r7) ----
// G feeds only the MFMA A-operand; A-lo term error ~1e-3 max per layer, within 6x margin.
// Halves agg write + gemm A-read. needed!=null: tail blocks run needed->list compaction.

__global__ __launch_bounds__(256)
void agg_kernel(const ushort* __restrict__ xh, const int* __restrict__ deg,
                const int* __restrict__ col,
                const int* __restrict__ list, const int* __restrict__ countp,
                ushort* __restrict__ aggh, int nodes,
                int aggblocks, const int* __restrict__ needed,
                int* __restrict__ wlist, int* __restrict__ wcnt, int rows_out) {
    if (needed && blockIdx.x >= aggblocks) {
        int i = (blockIdx.x - aggblocks) * 256 + threadIdx.x;
        if (i < NN && (i < rows_out || needed[i])) {
            int p = atomicAdd(wcnt, 1);
            wlist[p] = i;
        }
        return;
    }
    int i = (blockIdx.x * blockDim.x + threadIdx.x) >> 6;
    int lane = threadIdx.x & 63;
    int cnt = list ? *countp : nodes;
    if (i >= cnt) return;
    int node = list ? list[i] : i;
    int quad = lane >> 4;
    int ql   = lane & 15;
    int d = min(deg[node * DEGS], CAP);
    int start = node * CAP;
    int end = start + d;
    const uint4* xr = (const uint4*)xh;
    float a0=0,a1=0,a2=0,a3=0,a4=0,a5=0,a6=0,a7=0;
    int e = start;
    for (; e + 15 < end; e += 16) {
        int i0 = col[e + quad];
        int i1 = col[e + 4 + quad];
        int i2 = col[e + 8 + quad];
        int i3 = col[e + 12 + quad];
        uint4 u0 = xr[(size_t)i0 * 16 + ql];
        uint4 u1 = xr[(size_t)i1 * 16 + ql];
        uint4 u2 = xr[(size_t)i2 * 16 + ql];
        uint4 u3 = xr[(size_t)i3 * 16 + ql];
        a0 += (bf_lo(u0.x) + bf_lo(u1.x)) + (bf_lo(u2.x) + bf_lo(u3.x));
        a1 += (bf_hi(u0.x) + bf_hi(u1.x)) + (bf_hi(u2.x) + bf_hi(u3.x));
        a2 += (bf_lo(u0.y) + bf_lo(u1.y)) + (bf_lo(u2.y) + bf_lo(u3.y));
        a3 += (bf_hi(u0.y) + bf_hi(u1.y)) + (bf_hi(u2.y) + bf_hi(u3.y));
        a4 += (bf_lo(u0.z) + bf_lo(u1.z)) + (bf_lo(u2.z) + bf_lo(u3.z));
        a5 += (bf_hi(u0.z) + bf_hi(u1.z)) + (bf_hi(u2.z) + bf_hi(u3.z));
        a6 += (bf_lo(u0.w) + bf_lo(u1.w)) + (bf_lo(u2.w) + bf_lo(u3.w));
        a7 += (bf_hi(u0.w) + bf_hi(u1.w)) + (bf_hi(u2.w) + bf_hi(u3.w));
    }
    for (; e + 7 < end; e += 8) {
        int i0 = col[e + quad];
        int i1 = col[e + 4 + quad];
        uint4 u0 = xr[(size_t)i0 * 16 + ql];
        uint4 u1 = xr[(size_t)i1 * 16 + ql];
        a0 += bf_lo(u0.x) + bf_lo(u1.x); a1 += bf_hi(u0.x) + bf_hi(u1.x);
        a2 += bf_lo(u0.y) + bf_lo(u1.y); a3 += bf_hi(u0.y) + bf_hi(u1.y);
        a4 += bf_lo(u0.z) + bf_lo(u1.z); a5 += bf_hi(u0.z) + bf_hi(u1.z);
        a6 += bf_lo(u0.w) + bf_lo(u1.w); a7 += bf_hi(u0.w) + bf_hi(u1.w);
    }
    for (; e + 3 < end; e += 4) {
        uint4 u = xr[(size_t)col[e + quad] * 16 + ql];
        a0 += bf_lo(u.x); a1 += bf_hi(u.x);
        a2 += bf_lo(u.y); a3 += bf_hi(u.y);
        a4 += bf_lo(u.z); a5 += bf_hi(u.z);
        a6 += bf_lo(u.w); a7 += bf_hi(u.w);
    }
    int rem = end - e;
    if (quad < rem) {
        uint4 u = xr[(size_t)col[e + quad] * 16 + ql];
        a0 += bf_lo(u.x); a1 += bf_hi(u.x);
        a2 += bf_lo(u.y); a3 += bf_hi(u.y);
        a4 += bf_lo(u.z); a5 += bf_hi(u.z);
        a6 += bf_lo(u.w); a7 += bf_hi(u.w);
    }
    a0 += __shfl_xor(a0, 16, 64); a0 += __shfl_xor(a0, 32, 64);
    a1 += __shfl_xor(a1, 16, 64); a1 += __shfl_xor(a1, 32, 64);
    a2 += __shfl_xor(a2, 16, 64); a2 += __shfl_xor(a2, 32, 64);
    a3 += __shfl_xor(a3, 16, 64); a3 += __shfl_xor(a3, 32, 64);
    a4 += __shfl_xor(a4, 16, 64); a4 += __shfl_xor(a4, 32, 64);
    a5 += __shfl_xor(a5, 16, 64); a5 += __shfl_xor(a5, 32, 64);
    a6 += __shfl_xor(a6, 16, 64); a6 += __shfl_xor(a6, 32, 64);
    a7 += __shfl_xor(a7, 16, 64); a7 += __shfl_xor(a7, 32, 64);
    if (quad == 0) {
        float inv = 1.0f / (float)max(d, 1);
        float m[8] = {a0*inv, a1*inv, a2*inv, a3*inv, a4*inv, a5*inv, a6*inv, a7*inv};
        ushort h[8];
        #pragma unroll
        for (int j = 0; j < 8; ++j) h[j] = bf16_rn(m[j]);
        size_t off = (size_t)node * C + ql * 8;
        *(uint4*)(aggh + off) = make_uint4((unsigned)h[0] | ((unsigned)h[1] << 16),
                                           (unsigned)h[2] | ((unsigned)h[3] << 16),
                                           (unsigned)h[4] | ((unsigned)h[5] << 16),
                                           (unsigned)h[6] | ((unsigned)h[7] << 16));
    }
}

// ---- fused dual GEMM + bias + PReLU via split-bf16 MFMA ----
// out = prelu( A@Wl.T + bl + X@Wr.T ); A is bf16-hi ONLY (2 MFMAs: ahi@bhi, ahi@blo).
// X-side full precision: pre-split (Xh,Xl) or raw f32 (Xf, layer 0) split in-register.
// list!=null: rows from list[]; output scattered to original rows.

__global__ __launch_bounds__(256, 4)
void gemm_kernel(const ushort* __restrict__ Ag,
                 const ushort* __restrict__ Xh, const ushort* __restrict__ Xl,
                 const float* __restrict__ Xf,
                 const ushort* __restrict__ Wlh, const ushort* __restrict__ Wll,
                 const ushort* __restrict__ Wrh, const ushort* __restrict__ Wrl,
                 const float* __restrict__ bl, const float* __restrict__ slope,
                 const int* __restrict__ list, const int* __restrict__ countp,
                 float* __restrict__ outf, ushort* __restrict__ outh,
                 ushort* __restrict__ outl, int rows) {
    __shared__ ushort Ahi[64 * ASTRIDE];
    __shared__ ushort Alo[64 * ASTRIDE];
    int t = threadIdx.x;
    int lane = t & 63;
    int w = t >> 6;
    int l = lane & 15;
    int q = lane >> 4;
    int row0 = blockIdx.x * 64;
    int cnt = list ? min(*countp, rows) : rows;
    if (row0 >= cnt) return;

    f32x4 acc[4][2];
    #pragma unroll
    for (int mt = 0; mt < 4; ++mt)
        #pragma unroll
        for (int nt = 0; nt < 2; ++nt)
            acc[mt][nt] = (f32x4){0.f, 0.f, 0.f, 0.f};

    #pragma unroll
    for (int mat = 0; mat < 2; ++mat) {
        const ushort* WH = mat ? Wrh : Wlh;
        const ushort* WL = mat ? Wrl : Wll;

        bf16x8 bhi[2][4], blo[2][4];
        #pragma unroll
        for (int nt = 0; nt < 2; ++nt) {
            int n = w * 32 + nt * 16 + l;
            const ushort* wp = WH + (size_t)n * C + q * 8;
            const ushort* wq = WL + (size_t)n * C + q * 8;
            #pragma unroll
            for (int kb = 0; kb < 4; ++kb) {
                bhi[nt][kb] = *(const bf16x8*)(wp + kb * 32);
                blo[nt][kb] = *(const bf16x8*)(wq + kb * 32);
            }
        }

        __syncthreads();
        int ar = t >> 2;
        int aq = t & 3;
        int ridx = min(row0 + ar, cnt - 1);
        int r = list ? list[ridx] : ridx;
        ushort* dh = Ahi + ar * ASTRIDE + aq * 32;
        ushort* dl = Alo + ar * ASTRIDE + aq * 32;
        if (mat == 0) {
            // A-side: bf16-hi only
            const ushort* ph = Ag + (size_t)r * C + aq * 32;
            #pragma unroll
            for (int i = 0; i < 4; ++i)
                *(uint4*)(dh + i * 8) = *(const uint4*)(ph + i * 8);
        } else if (Xf) {
            const float* px = Xf + (size_t)r * C + aq * 32;
            #pragma unroll
            for (int i = 0; i < 8; ++i) {
                f32x4 v = *(const f32x4*)(px + i * 4);
                ushort h0, h1, h2, h3, l0, l1, l2, l3;
                split_bf16(v.x, h0, l0);
                split_bf16(v.y, h1, l1);
                split_bf16(v.z, h2, l2);
                split_bf16(v.w, h3, l3);
                *(uint2*)(dh + i * 4) = make_uint2((unsigned)h0 | ((unsigned)h1 << 16),
                                                   (unsigned)h2 | ((unsigned)h3 << 16));
                *(uint2*)(dl + i * 4) = make_uint2((unsigned)l0 | ((unsigned)l1 << 16),
                                                   (unsigned)l2 | ((unsigned)l3 << 16));
            }
        } else {
            const ushort* ph = Xh + (size_t)r * C + aq * 32;
            const ushort* pl = Xl + (size_t)r * C + aq * 32;
            #pragma unroll
            for (int i = 0; i < 4; ++i) {
                *(uint4*)(dh + i * 8) = *(const uint4*)(ph + i * 8);
                *(uint4*)(dl + i * 8) = *(const uint4*)(pl + i * 8);
            }
        }
        __syncthreads();

        #pragma unroll
        for (int kb = 0; kb < 4; ++kb) {
            #pragma unroll
            for (int mt = 0; mt < 4; ++mt) {
                int off = (mt * 16 + l) * ASTRIDE + kb * 32 + q * 8;
                bf16x8 ahi = *(const bf16x8*)(Ahi + off);
                #pragma unroll
                for (int nt = 0; nt < 2; ++nt) {
                    acc[mt][nt] = __builtin_amdgcn_mfma_f32_16x16x32_bf16(ahi, bhi[nt][kb], acc[mt][nt], 0, 0, 0);
                    if (mat == 1) {
                        bf16x8 alo = *(const bf16x8*)(Alo + off);
                        acc[mt][nt] = __builtin_amdgcn_mfma_f32_16x16x32_bf16(alo, bhi[nt][kb], acc[mt][nt], 0, 0, 0);
                    }
                    acc[mt][nt] = __builtin_amdgcn_mfma_f32_16x16x32_bf16(ahi, blo[nt][kb], acc[mt][nt], 0, 0, 0);
                }
            }
        }
    }

    #pragma unroll
    for (int nt = 0; nt < 2; ++nt) {
        int n = w * 32 + nt * 16 + l;
        float b = bl[n], s = slope[n];
        #pragma unroll
        for (int mt = 0; mt < 4; ++mt) {
            #pragma unroll
            for (int rg = 0; rg < 4; ++rg) {
                int ridx = row0 + mt * 16 + q * 4 + rg;
                if (ridx < cnt) {
                    int r = list ? list[ridx] : ridx;
                    float v = acc[mt][nt][rg] + b;
                    v = v > 0.f ? v : s * v;
                    if (outf) {
                        outf[(size_t)r * C + n] = v;
                    } else {
                        ushort hh, ll;
                        split_bf16(v, hh, ll);
                        outh[(size_t)r * C + n] = hh;
                        outl[(size_t)r * C + n] = ll;
                    }
                }
            }
        }
    }
}

// ---- fused layer (r5-proven, layer 2 only: 16 blocks, occupancy irrelevant) ----
// Gathers+means the A operand in-register during staging (full hi/lo split precision),
// then dual GEMM + bias + PReLU -> f32 out. Deletes agg2 dispatch + G round-trip.

__global__ __launch_bounds__(256)
void fused_kernel(const ushort* __restrict__ Gsrc,
                  const int* __restrict__ deg, const int* __restrict__ col,
                  const ushort* __restrict__ Xh, const ushort* __restrict__ Xl,
                  const ushort* __restrict__ Wlh, const ushort* __restrict__ Wll,
                  const ushort* __restrict__ Wrh, const ushort* __restrict__ Wrl,
                  const float* __restrict__ bl, const float* __restrict__ slope,
                  float* __restrict__ outf, int rows) {
    __shared__ ushort Ahi[64 * ASTRIDE];
    __shared__ ushort Alo[64 * ASTRIDE];
    int t = threadIdx.x;
    int lane = t & 63;
    int w = t >> 6;
    int l = lane & 15;
    int q = lane >> 4;
    int row0 = blockIdx.x * 64;
    if (row0 >= rows) return;

    f32x4 acc[4][2];
    #pragma unroll
    for (int mt = 0; mt < 4; ++mt)
        #pragma unroll
        for (int nt = 0; nt < 2; ++nt)
            acc[mt][nt] = (f32x4){0.f, 0.f, 0.f, 0.f};

    #pragma unroll
    for (int mat = 0; mat < 2; ++mat) {
        const ushort* WH = mat ? Wrh : Wlh;
        const ushort* WL = mat ? Wrl : Wll;

        bf16x8 bhi[2][4], blo[2][4];
        #pragma unroll
        for (int nt = 0; nt < 2; ++nt) {
            int n = w * 32 + nt * 16 + l;
            const ushort* wp = WH + (size_t)n * C + q * 8;
            const ushort* wq = WL + (size_t)n * C + q * 8;
            #pragma unroll
            for (int kb = 0; kb < 4; ++kb) {
                bhi[nt][kb] = *(const bf16x8*)(wp + kb * 32);
                blo[nt][kb] = *(const bf16x8*)(wq + kb * 32);
            }
        }

        __syncthreads();
        int ar = t >> 2;
        int aq = t & 3;
        int r = min(row0 + ar, rows - 1);
        ushort* dh = Ahi + ar * ASTRIDE + aq * 32;
        ushort* dl = Alo + ar * ASTRIDE + aq * 32;
        if (mat == 0) {
            int d = min(deg[r * DEGS], CAP);
            int base = r * CAP;
            float s[32];
            #pragma unroll
            for (int j = 0; j < 32; ++j) s[j] = 0.f;
#define ACC8(k, u, v) \
            s[(k)+0] += bf_lo((u).x) + bf_lo((v).x); s[(k)+1] += bf_hi((u).x) + bf_hi((v).x); \
            s[(k)+2] += bf_lo((u).y) + bf_lo((v).y); s[(k)+3] += bf_hi((u).y) + bf_hi((v).y); \
            s[(k)+4] += bf_lo((u).z) + bf_lo((v).z); s[(k)+5] += bf_hi((u).z) + bf_hi((v).z); \
            s[(k)+6] += bf_lo((u).w) + bf_lo((v).w); s[(k)+7] += bf_hi((u).w) + bf_hi((v).w);
#define ACC8S(k, u) \
            s[(k)+0] += bf_lo((u).x); s[(k)+1] += bf_hi((u).x); \
            s[(k)+2] += bf_lo((u).y); s[(k)+3] += bf_hi((u).y); \
            s[(k)+4] += bf_lo((u).z); s[(k)+5] += bf_hi((u).z); \
            s[(k)+6] += bf_lo((u).w); s[(k)+7] += bf_hi((u).w);
            int e = 0;
            for (; e + 1 < d; e += 2) {
                int2 c01 = *(const int2*)(col + base + e);
                const uint4* p0 = (const uint4*)Gsrc + (size_t)c01.x * 16 + aq * 4;
                const uint4* p1 = (const uint4*)Gsrc + (size_t)c01.y * 16 + aq * 4;
                uint4 a0 = p0[0], a1 = p0[1], a2 = p0[2], a3 = p0[3];
                uint4 b0 = p1[0], b1 = p1[1], b2 = p1[2], b3 = p1[3];
                ACC8(0, a0, b0) ACC8(8, a1, b1) ACC8(16, a2, b2) ACC8(24, a3, b3)
            }
            if (e < d) {
                int c0 = col[base + e];
                const uint4* p0 = (const uint4*)Gsrc + (size_t)c0 * 16 + aq * 4;
                uint4 a0 = p0[0], a1 = p0[1], a2 = p0[2], a3 = p0[3];
                ACC8S(0, a0) ACC8S(8, a1) ACC8S(16, a2) ACC8S(24, a3)
            }
#undef ACC8
#undef ACC8S
            float inv = 1.0f / (float)max(d, 1);
            #pragma unroll
            for (int i = 0; i < 4; ++i) {
                ushort h[8], o[8];
                #pragma unroll
                for (int j = 0; j < 8; ++j) split_bf16(s[i * 8 + j] * inv, h[j], o[j]);
                *(uint4*)(dh + i * 8) = make_uint4((unsigned)h[0] | ((unsigned)h[1] << 16),
                                                   (unsigned)h[2] | ((unsigned)h[3] << 16),
                                                   (unsigned)h[4] | ((unsigned)h[5] << 16),
                                                   (unsigned)h[6] | ((unsigned)h[7] << 16));
                *(uint4*)(dl + i * 8) = make_uint4((unsigned)o[0] | ((unsigned)o[1] << 16),
                                                   (unsigned)o[2] | ((unsigned)o[3] << 16),
                                                   (unsigned)o[4] | ((unsigned)o[5] << 16),
                                                   (unsigned)o[6] | ((unsigned)o[7] << 16));
            }
        } else {
            const ushort* ph = Xh + (size_t)r * C + aq * 32;
            const ushort* pl = Xl + (size_t)r * C + aq * 32;
            #pragma unroll
            for (int i = 0; i < 4; ++i) {
                *(uint4*)(dh + i * 8) = *(const uint4*)(ph + i * 8);
                *(uint4*)(dl + i * 8) = *(const uint4*)(pl + i * 8);
            }
        }
        __syncthreads();

        #pragma unroll
        for (int kb = 0; kb < 4; ++kb) {
            #pragma unroll
            for (int mt = 0; mt < 4; ++mt) {
                int off = (mt * 16 + l) * ASTRIDE + kb * 32 + q * 8;
                bf16x8 ahi = *(const bf16x8*)(Ahi + off);
                bf16x8 alo = *(const bf16x8*)(Alo + off);
                #pragma unroll
                for (int nt = 0; nt < 2; ++nt) {
                    acc[mt][nt] = __builtin_amdgcn_mfma_f32_16x16x32_bf16(ahi, bhi[nt][kb], acc[mt][nt], 0, 0, 0);
                    acc[mt][nt] = __builtin_amdgcn_mfma_f32_16x16x32_bf16(alo, bhi[nt][kb], acc[mt][nt], 0, 0, 0);
                    acc[mt][nt] = __builtin_amdgcn_mfma_f32_16x16x32_bf16(ahi, blo[nt][kb], acc[mt][nt], 0, 0, 0);
                }
            }
        }
    }

    #pragma unroll
    for (int nt = 0; nt < 2; ++nt) {
        int n = w * 32 + nt * 16 + l;
        float b = bl[n], s = slope[n];
        #pragma unroll
        for (int mt = 0; mt < 4; ++mt) {
            #pragma unroll
            for (int rg = 0; rg < 4; ++rg) {
                int ridx = row0 + mt * 16 + q * 4 + rg;
                if (ridx < rows) {
                    float v = acc[mt][nt][rg] + b;
                    v = v > 0.f ? v : s * v;
                    outf[(size_t)ridx * C + n] = v;
                }
            }
        }
    }
}

// ---------------- launch ----------------

extern "C" void kernel_launch(void* const* d_in, const int* in_sizes, int n_in,
                              void* d_out, int out_size, void* d_ws, size_t ws_size,
                              hipStream_t stream) {
    const float* x   = (const float*)d_in[0];
    const int*   src = (const int*)d_in[1];
    const int*   dst = src + NE;
    const float* Wl[3] = {(const float*)d_in[3], (const float*)d_in[7],  (const float*)d_in[11]};
    const float* bl[3] = {(const float*)d_in[4], (const float*)d_in[8],  (const float*)d_in[12]};
    const float* Wr[3] = {(const float*)d_in[5], (const float*)d_in[9],  (const float*)d_in[13]};
    const float* sl[3] = {(const float*)d_in[6], (const float*)d_in[10], (const float*)d_in[14]};

    int*   deg     = (int*)d_ws;             // NN*DEGS = 800000 ints (1 counter per 64B line)
    int*   needed  = deg + NN * DEGS;        // 50016
    int*   cnt     = needed + 50016;         // 16 (one used)
    int*   col     = cnt + 16;               // NN*CAP = 3.2M ints
    int*   list    = col + NN * CAP;         // 50016
    ushort* Whs    = (ushort*)(list + 50016);    // 6*16384 pre-split W hi
    ushort* Wls    = Whs + 6 * 16384;        // 6*16384 pre-split W lo
    ushort* Gh     = Wls + 6 * 16384;        // agg hi, NN*C (hi only now)
    ushort* Ah     = Gh + (size_t)NN * C;    // ping hi (x-hi from prep; layer-1 out)
    ushort* Al     = Ah + (size_t)NN * C;    // ping lo (layer-1 out only)
    ushort* Bh     = Al + (size_t)NN * C;    // pong hi
    ushort* Bl     = Bh + (size_t)NN * C;    // pong lo

    int rows_out = out_size / C;             // 1024

    // zero deg (padded) + needed + cnt (contiguous)
    hipMemsetAsync(deg, 0, (NN * DEGS + 50016 + 16) * sizeof(int), stream);

    // W order: Wl0, Wr0, Wl1, Wr1, Wl2, Wr2
    prep_kernel<<<EP16 + SPLITB + WB, 256, 0, stream>>>(
        src, dst, x, Wl[0], Wr[0], Wl[1], Wr[1], Wl[2], Wr[2],
        deg, col, Ah, Whs, Wls, needed, rows_out);

    // layer 0 (full): x -> B; compaction rides the tail blocks of agg0
    agg_kernel<<<AGG0B + CB, 256, 0, stream>>>(Ah, deg, col, nullptr, nullptr, Gh, NN,
                                               AGG0B, needed, list, cnt, rows_out);
    gemm_kernel<<<(NN + 63) / 64, 256, 0, stream>>>(Gh, nullptr, nullptr, x,
                                                    Whs + 0 * 16384, Wls + 0 * 16384,
                                                    Whs + 1 * 16384, Wls + 1 * 16384,
                                                    bl[0], sl[0], nullptr, nullptr,
                                                    nullptr, Bh, Bl, NN);

    // layer 1 (pruned to needed list): B -> A (scattered at original rows)
    agg_kernel<<<AGG0B, 256, 0, stream>>>(Bh, deg, col, list, cnt, Gh, NN,
                                          AGG0B, nullptr, nullptr, nullptr, rows_out);
    gemm_kernel<<<(NN + 63) / 64, 256, 0, stream>>>(Gh, Bh, Bl, nullptr,
                                                    Whs + 2 * 16384, Wls + 2 * 16384,
                                                    Whs + 3 * 16384, Wls + 3 * 16384,
                                                    bl[1], sl[1], list, cnt,
                                                    nullptr, Ah, Al, NN);

    // layer 2 (first rows_out nodes): fused gather+GEMM, A -> d_out (f32)
    fused_kernel<<<(rows_out + 63) / 64, 256, 0, stream>>>(Ah, deg, col, Ah, Al,
                                                           Whs + 4 * 16384, Wls + 4 * 16384,
                                                           Whs + 5 * 16384, Wls + 5 * 16384,
                                                           bl[2], sl[2],
                                                           (float*)d_out, rows_out);
}